// Round 17
// baseline (1137.748 us; speedup 1.0000x reference)
//
#include <hip/hip_runtime.h>
#include <hip/hip_bf16.h>
#include <math.h>

// ---------------------------------------------------------------------------
// Model dims: B=2, Cn=3, HI=WI=224, S=196, P=256, D=384, H_TOK=4
// DEPTH=12, H_VIT=6 (dh=64), HID=1536, NCLS=1000
// x layout: [394][384] f32 (rows 0,197 = cls).
// Weights are read DIRECTLY as f32 (converted to bf16 fragments in-register;
// each weight byte is used exactly once per call, so the R16 cvt pre-pass
// (127 MB traffic, 52 us) was strictly redundant).
// ---------------------------------------------------------------------------

typedef __attribute__((ext_vector_type(8))) short short8b;
typedef __attribute__((ext_vector_type(4))) float f32x4;

static __device__ __forceinline__ float gelu_exact(float v) {
    return 0.5f * v * (1.0f + erff(v * 0.70710678118654752440f));
}
static __device__ __forceinline__ short bf16s(float f) {
    __hip_bfloat16 h = __float2bfloat16(f);
    return *reinterpret_cast<short*>(&h);
}
// load 8 consecutive f32 weights -> bf16 fragment (same rounding as cvt path)
static __device__ __forceinline__ short8b ldw8(const float* __restrict__ p) {
    float4 v0 = *reinterpret_cast<const float4*>(p);
    float4 v1 = *reinterpret_cast<const float4*>(p + 4);
    short8b o;
    o[0]=bf16s(v0.x); o[1]=bf16s(v0.y); o[2]=bf16s(v0.z); o[3]=bf16s(v0.w);
    o[4]=bf16s(v1.x); o[5]=bf16s(v1.y); o[6]=bf16s(v1.z); o[7]=bf16s(v1.w);
    return o;
}

// ---------------------------------------------------------------------------
// Setup: zero vT key pad (blocks 0..80) + prep W2/b2 + x cls rows (81..85).
// ---------------------------------------------------------------------------
__global__ __launch_bounds__(256) void prep_all_k(
    __hip_bfloat16* __restrict__ vT,
    const float* __restrict__ ap_in_w, const float* __restrict__ ap_in_b,
    const float* __restrict__ fp_w, const float* __restrict__ fp_b,
    const float* __restrict__ cls, const float* __restrict__ pos,
    float* __restrict__ W2, float* __restrict__ b2, float* __restrict__ xs)
{
    if (blockIdx.x < 81) {
        int t = blockIdx.x * 256 + threadIdx.x;
        if (t < 12*64*27) {
            int c = t % 27, r = t / 27;
            vT[(long)r*224 + 197 + c] = __float2bfloat16(0.f);
        }
        return;
    }
    int o = (blockIdx.x - 81) * 256 + threadIdx.x;
    if (o < 384) {
        float v = cls[o] + pos[o];
        xs[o] = v;
        xs[197*384 + o] = v;
    }
    if (o >= 1152) return;
    const float* ar = ap_in_w + (long)o * 384;
    float a0 = 0.f, a1 = 0.f, a2 = 0.f, ab = ap_in_b[o];
    for (int d = 0; d < 384; ++d) {
        float aw = ar[d];
        a0 = fmaf(aw, fp_w[d*3+0], a0);
        a1 = fmaf(aw, fp_w[d*3+1], a1);
        a2 = fmaf(aw, fp_w[d*3+2], a2);
        ab = fmaf(aw, fp_b[d], ab);
    }
    W2[o*3+0] = a0; W2[o*3+1] = a1; W2[o*3+2] = a2; b2[o] = ab;
}

// ---------------------------------------------------------------------------
__global__ __launch_bounds__(64) void prep_head_k(
    const float* __restrict__ W2, const float* __restrict__ b2,
    float* __restrict__ hGm)
{
    int h = blockIdx.x;
    int lane = threadIdx.x;
    float G00=0,G01=0,G02=0,G10=0,G11=0,G12=0,G20=0,G21=0,G22=0;
    float u0=0,u1=0,u2=0,w0=0,w1=0,w2=0,c0=0;
    for (int d = lane; d < 96; d += 64) {
        int oq = h*96 + d, ok = 384 + h*96 + d;
        float q0=W2[oq*3],q1=W2[oq*3+1],q2=W2[oq*3+2];
        float k0=W2[ok*3],k1=W2[ok*3+1],k2=W2[ok*3+2];
        float bq=b2[oq], bk=b2[ok];
        G00=fmaf(q0,k0,G00); G01=fmaf(q0,k1,G01); G02=fmaf(q0,k2,G02);
        G10=fmaf(q1,k0,G10); G11=fmaf(q1,k1,G11); G12=fmaf(q1,k2,G12);
        G20=fmaf(q2,k0,G20); G21=fmaf(q2,k1,G21); G22=fmaf(q2,k2,G22);
        u0=fmaf(q0,bk,u0); u1=fmaf(q1,bk,u1); u2=fmaf(q2,bk,u2);
        w0=fmaf(k0,bq,w0); w1=fmaf(k1,bq,w1); w2=fmaf(k2,bq,w2);
        c0=fmaf(bq,bk,c0);
    }
    float vals[16] = {G00,G01,G02,u0, G10,G11,G12,u1, G20,G21,G22,u2, w0,w1,w2,c0};
    const float sc = 0.10206207261596577f; // 1/sqrt(96)
    #pragma unroll
    for (int q = 0; q < 16; ++q) {
        float v = vals[q];
        for (int off = 32; off; off >>= 1) v += __shfl_down(v, off);
        if (lane == 0) hGm[h*16 + q] = v * sc;
    }
}

// ---------------------------------------------------------------------------
// Tokenizer attention, 1-pass, 1024 threads, interleaved j-split
// (validated R14-R16: conflict-free).
// ---------------------------------------------------------------------------
__global__ __launch_bounds__(1024) void tok_attn_k(
    const float* __restrict__ img, const float* __restrict__ hGm,
    const float* __restrict__ W2, const float* __restrict__ b2,
    __hip_bfloat16* __restrict__ pooledb)
{
    int s = blockIdx.x, h = blockIdx.y, b = blockIdx.z;
    int tid = threadIdx.x;
    __shared__ float4 pxm[256];
    __shared__ float4 ylds[256];
    __shared__ float  tsum[3];

    if (tid < 256) {
        int gy = s / 14, gx = s - gy*14;
        int row = gy*16 + (tid >> 4), col = gx*16 + (tid & 15);
        long base = ((long)b*3*224 + row)*224 + col;
        float p0 = img[base];
        float p1 = img[base + 224*224];
        float p2 = img[base + 2*224*224];
        const float4* M4 = reinterpret_cast<const float4*>(hGm) + h*4;
        float4 r0 = M4[0], r1 = M4[1], r2 = M4[2], r3 = M4[3];
        float y0 = fmaf(p0,r0.x, fmaf(p1,r0.y, fmaf(p2,r0.z, r0.w)));
        float y1 = fmaf(p0,r1.x, fmaf(p1,r1.y, fmaf(p2,r1.z, r1.w)));
        float y2 = fmaf(p0,r2.x, fmaf(p1,r2.y, fmaf(p2,r2.z, r2.w)));
        float y3 = fmaf(p0,r3.x, fmaf(p1,r3.y, fmaf(p2,r3.z, r3.w)));
        ylds[tid] = make_float4(y0,y1,y2,y3);
        pxm[tid]  = make_float4(p0,p1,p2,0.f);
    }
    __syncthreads();

    int i = tid >> 2, sub = tid & 3;
    float4 P = pxm[i];
    float li = 0.f, w0 = 0.f, w1 = 0.f, w2 = 0.f;
    #pragma unroll 4
    for (int jj = 0; jj < 64; ++jj) {
        int j = jj*4 + sub;
        float4 Y = ylds[j];
        float4 q = pxm[j];
        float scr = fmaf(P.x,Y.x, fmaf(P.y,Y.y, fmaf(P.z,Y.z, Y.w)));
        float e = __expf(scr);
        li += e;
        w0 = fmaf(e, q.x, w0);
        w1 = fmaf(e, q.y, w1);
        w2 = fmaf(e, q.z, w2);
    }
    li += __shfl_xor(li, 1); li += __shfl_xor(li, 2);
    w0 += __shfl_xor(w0, 1); w0 += __shfl_xor(w0, 2);
    w1 += __shfl_xor(w1, 1); w1 += __shfl_xor(w1, 2);
    w2 += __shfl_xor(w2, 1); w2 += __shfl_xor(w2, 2);
    float rl = 1.f / li;
    __syncthreads();
    if (sub == 0) pxm[i] = make_float4(w0*rl, w1*rl, w2*rl, 0.f);
    __syncthreads();

    int w = tid >> 6, lane = tid & 63;
    if (w < 3) {
        float prt = 0.f;
        for (int j = lane; j < 256; j += 64)
            prt += reinterpret_cast<const float*>(&pxm[j])[w];
        for (int off = 32; off; off >>= 1) prt += __shfl_down(prt, off);
        if (lane == 0) tsum[w] = prt;
    }
    __syncthreads();

    if (tid < 96) {
        int o = 768 + h*96 + tid;
        float v = (W2[o*3]*tsum[0] + W2[o*3+1]*tsum[1] + W2[o*3+2]*tsum[2]) * (1.f/256.f)
                  + b2[o];
        pooledb[((long)(b*196 + s))*384 + h*96 + tid] = __float2bfloat16(v);
    }
}

// ---------------------------------------------------------------------------
// Tokenizer out-proj -> x directly, pos-embed fused. W = ap_out_w f32 direct.
// ---------------------------------------------------------------------------
__global__ __launch_bounds__(64) void outproj_x_k(
    const __hip_bfloat16* __restrict__ A, const float* __restrict__ W,
    const float* __restrict__ bias, const float* __restrict__ pos,
    float* __restrict__ xs)
{
    int l = threadIdx.x;
    int m0 = blockIdx.x * 16, n0 = blockIdx.y * 64;
    int arow = m0 + (l & 15); if (arow >= 392) arow = 391;
    const __hip_bfloat16* Ap = A + (long)arow * 384 + ((l >> 4) << 3);
    const float* W0 = W + (long)(n0 + (l & 15)) * 384 + ((l >> 4) << 3);

    f32x4 acc[4];
    #pragma unroll
    for (int f = 0; f < 4; ++f) acc[f] = f32x4{0.f,0.f,0.f,0.f};
    #pragma unroll 4
    for (int kt = 0; kt < 12; ++kt) {
        int k = kt << 5;
        short8b a  = *reinterpret_cast<const short8b*>(Ap + k);
        short8b b0 = ldw8(W0 + k);
        short8b b1 = ldw8(W0 + 16L*384 + k);
        short8b b2 = ldw8(W0 + 32L*384 + k);
        short8b b3 = ldw8(W0 + 48L*384 + k);
        acc[0] = __builtin_amdgcn_mfma_f32_16x16x32_bf16(a, b0, acc[0], 0, 0, 0);
        acc[1] = __builtin_amdgcn_mfma_f32_16x16x32_bf16(a, b1, acc[1], 0, 0, 0);
        acc[2] = __builtin_amdgcn_mfma_f32_16x16x32_bf16(a, b2, acc[2], 0, 0, 0);
        acc[3] = __builtin_amdgcn_mfma_f32_16x16x32_bf16(a, b3, acc[3], 0, 0, 0);
    }

    int cl = l & 15;
    int rbase = m0 + ((l >> 4) << 2);
    #pragma unroll
    for (int f = 0; f < 4; ++f) {
        int n = n0 + f*16 + cl;
        float bv = bias[n];
        #pragma unroll
        for (int r = 0; r < 4; ++r) {
            int m = rbase + r;
            if (m >= 392) continue;
            int b = m / 196;
            int srow = m - 196*b + 1;
            xs[(long)(m + b + 1)*384 + n] = acc[f][r] + bv + pos[(long)srow*384 + n];
        }
    }
}

// ---------------------------------------------------------------------------
// Fused LayerNorm + MFMA GEMM (K=384), W f32 direct. Validated structure R3/R8.
// EPI=1: qkv scatter to qb/kb (x0.125 on q) /vT.  EPI=2: gelu -> bf16 C.
// ---------------------------------------------------------------------------
template<int EPI>
__global__ __launch_bounds__(64) void ln_gemm_k(
    const float* __restrict__ x, const float* __restrict__ g,
    const float* __restrict__ b, const float* __restrict__ W,
    const float* __restrict__ bias,
    __hip_bfloat16* __restrict__ o0, __hip_bfloat16* __restrict__ o1,
    __hip_bfloat16* __restrict__ o2, int M, int N)
{
    int l = threadIdx.x;
    int m0 = blockIdx.x * 16, n0 = blockIdx.y * 64;
    int cl = l & 15, hi = l >> 4;
    int row = m0 + cl; if (row >= M) row = M - 1;
    const float* xp = x + (long)row*384 + (hi << 3);

    float sum = 0.f, sq = 0.f;
    #pragma unroll
    for (int t = 0; t < 12; ++t) {
        float4 v0 = *reinterpret_cast<const float4*>(xp + t*32);
        float4 v1 = *reinterpret_cast<const float4*>(xp + t*32 + 4);
        sum += v0.x+v0.y+v0.z+v0.w + v1.x+v1.y+v1.z+v1.w;
        sq  += v0.x*v0.x+v0.y*v0.y+v0.z*v0.z+v0.w*v0.w
             + v1.x*v1.x+v1.y*v1.y+v1.z*v1.z+v1.w*v1.w;
    }
    sum += __shfl_xor(sum, 16); sum += __shfl_xor(sum, 32);
    sq  += __shfl_xor(sq, 16);  sq  += __shfl_xor(sq, 32);
    float mean = sum * (1.f/384.f);
    float var  = sq * (1.f/384.f) - mean*mean;
    float rstd = rsqrtf(var + 1e-6f);

    const float* Wp = W + (long)(n0 + cl)*384 + (hi << 3);
    f32x4 acc[4];
    #pragma unroll
    for (int f = 0; f < 4; ++f) acc[f] = f32x4{0.f,0.f,0.f,0.f};

    #pragma unroll 2
    for (int t = 0; t < 12; ++t) {
        int k = t*32 + (hi << 3);
        float4 v0 = *reinterpret_cast<const float4*>(xp + t*32);
        float4 v1 = *reinterpret_cast<const float4*>(xp + t*32 + 4);
        float4 g0 = *reinterpret_cast<const float4*>(g + k);
        float4 g1 = *reinterpret_cast<const float4*>(g + k + 4);
        float4 bb0 = *reinterpret_cast<const float4*>(b + k);
        float4 bb1 = *reinterpret_cast<const float4*>(b + k + 4);
        short8b a;
        a[0] = bf16s(fmaf((v0.x-mean)*rstd, g0.x, bb0.x));
        a[1] = bf16s(fmaf((v0.y-mean)*rstd, g0.y, bb0.y));
        a[2] = bf16s(fmaf((v0.z-mean)*rstd, g0.z, bb0.z));
        a[3] = bf16s(fmaf((v0.w-mean)*rstd, g0.w, bb0.w));
        a[4] = bf16s(fmaf((v1.x-mean)*rstd, g1.x, bb1.x));
        a[5] = bf16s(fmaf((v1.y-mean)*rstd, g1.y, bb1.y));
        a[6] = bf16s(fmaf((v1.z-mean)*rstd, g1.z, bb1.z));
        a[7] = bf16s(fmaf((v1.w-mean)*rstd, g1.w, bb1.w));
        short8b w0 = ldw8(Wp + t*32);
        short8b w1 = ldw8(Wp + 16L*384 + t*32);
        short8b w2 = ldw8(Wp + 32L*384 + t*32);
        short8b w3 = ldw8(Wp + 48L*384 + t*32);
        acc[0] = __builtin_amdgcn_mfma_f32_16x16x32_bf16(a, w0, acc[0], 0, 0, 0);
        acc[1] = __builtin_amdgcn_mfma_f32_16x16x32_bf16(a, w1, acc[1], 0, 0, 0);
        acc[2] = __builtin_amdgcn_mfma_f32_16x16x32_bf16(a, w2, acc[2], 0, 0, 0);
        acc[3] = __builtin_amdgcn_mfma_f32_16x16x32_bf16(a, w3, acc[3], 0, 0, 0);
    }

    int rb = hi << 2;
    #pragma unroll
    for (int f = 0; f < 4; ++f) {
        int n = n0 + f*16 + cl;
        float bv = bias[n];
        #pragma unroll
        for (int r = 0; r < 4; ++r) {
            int m = m0 + rb + r;
            if (m >= M) continue;
            float v = acc[f][r] + bv;
            if (EPI == 1) {
                int bb = (m >= 197) ? 1 : 0;
                int tokr = m - bb*197;
                if (n < 384) {
                    int h = n >> 6, ch = n & 63;
                    o0[((long)(bb*6 + h)*208 + tokr)*64 + ch] = __float2bfloat16(v * 0.125f);
                } else if (n < 768) {
                    int nn = n - 384, h = nn >> 6, ch = nn & 63;
                    o1[((long)(bb*6 + h)*208 + tokr)*64 + ch] = __float2bfloat16(v);
                } else {
                    int nn = n - 768, h = nn >> 6, ch = nn & 63;
                    o2[((long)(bb*6 + h)*64 + ch)*224 + tokr] = __float2bfloat16(v);
                }
            } else { // EPI == 2
                o0[(long)m*N + n] = __float2bfloat16(gelu_exact(v));
            }
        }
    }
}

// ---------------------------------------------------------------------------
// Fused flash attention (validated R3/R8). grid (13 qt, 12 bh), 1 wave.
// ---------------------------------------------------------------------------
__global__ __launch_bounds__(64) void attn_flash_k(
    const __hip_bfloat16* __restrict__ qb, const __hip_bfloat16* __restrict__ kb,
    const __hip_bfloat16* __restrict__ vT, __hip_bfloat16* __restrict__ attnb)
{
    __shared__ __align__(16) short lp[16*232];
    int l = threadIdx.x;
    int qt = blockIdx.x, bh = blockIdx.y;
    int q0 = qt * 16;
    int cl = l & 15, hi = l >> 4;

    if (l < 32) {
        int row = l >> 1, hf = l & 1;
        *reinterpret_cast<int4*>(lp + row*232 + 208 + hf*8) = int4{0,0,0,0};
    }

    const __hip_bfloat16* Qp = qb + ((long)bh*208 + q0 + cl)*64 + (hi << 3);
    const __hip_bfloat16* Kp = kb + ((long)bh*208 + cl)*64 + (hi << 3);
    f32x4 s[13];
    #pragma unroll
    for (int f = 0; f < 13; ++f) s[f] = f32x4{0.f,0.f,0.f,0.f};
    #pragma unroll
    for (int kt = 0; kt < 2; ++kt) {
        short8b a = *reinterpret_cast<const short8b*>(Qp + kt*32);
        #pragma unroll
        for (int f = 0; f < 13; ++f) {
            short8b kk = *reinterpret_cast<const short8b*>(Kp + (long)f*16*64 + kt*32);
            s[f] = __builtin_amdgcn_mfma_f32_16x16x32_bf16(a, kk, s[f], 0, 0, 0);
        }
    }
    if (cl >= 5) s[12] = f32x4{-1e30f,-1e30f,-1e30f,-1e30f};

    #pragma unroll
    for (int r = 0; r < 4; ++r) {
        float m = s[0][r];
        #pragma unroll
        for (int f = 1; f < 13; ++f) m = fmaxf(m, s[f][r]);
        m = fmaxf(m, __shfl_xor(m, 1));
        m = fmaxf(m, __shfl_xor(m, 2));
        m = fmaxf(m, __shfl_xor(m, 4));
        m = fmaxf(m, __shfl_xor(m, 8));
        float e[13]; float ssum = 0.f;
        #pragma unroll
        for (int f = 0; f < 13; ++f) { e[f] = __expf(s[f][r] - m); ssum += e[f]; }
        ssum += __shfl_xor(ssum, 1);
        ssum += __shfl_xor(ssum, 2);
        ssum += __shfl_xor(ssum, 4);
        ssum += __shfl_xor(ssum, 8);
        float ri = 1.f / ssum;
        int prow = (hi << 2) + r;
        #pragma unroll
        for (int f = 0; f < 13; ++f)
            lp[prow*232 + f*16 + cl] = bf16s(e[f] * ri);
    }
    __syncthreads();

    f32x4 o[4];
    #pragma unroll
    for (int f = 0; f < 4; ++f) o[f] = f32x4{0.f,0.f,0.f,0.f};
    const __hip_bfloat16* Vp = vT + ((long)bh*64 + cl)*224 + (hi << 3);
    #pragma unroll
    for (int kt = 0; kt < 7; ++kt) {
        short8b pa = *reinterpret_cast<const short8b*>(&lp[cl*232 + (hi << 3) + kt*32]);
        #pragma unroll
        for (int f2 = 0; f2 < 4; ++f2) {
            short8b vb = *reinterpret_cast<const short8b*>(Vp + (long)f2*16*224 + kt*32);
            o[f2] = __builtin_amdgcn_mfma_f32_16x16x32_bf16(pa, vb, o[f2], 0, 0, 0);
        }
    }

    int b = bh / 6, h = bh - b*6;
    #pragma unroll
    for (int f2 = 0; f2 < 4; ++f2) {
        int ch = h*64 + f2*16 + cl;
        #pragma unroll
        for (int r = 0; r < 4; ++r) {
            int qr = q0 + (hi << 2) + r;
            if (qr < 197)
                attnb[((long)(b*197 + qr))*384 + ch] = __float2bfloat16(o[f2][r]);
        }
    }
}

// ---------------------------------------------------------------------------
// proj: MFMA GEMM, 1 wave/block, 16x64 tile, W f32 direct, +bias+residual.
// ---------------------------------------------------------------------------
__global__ __launch_bounds__(64) void proj_k(
    const __hip_bfloat16* __restrict__ A, const float* __restrict__ W,
    const float* __restrict__ bias, float* __restrict__ x)
{
    int l = threadIdx.x;
    int m0 = blockIdx.x * 16, n0 = blockIdx.y * 64;
    int arow = m0 + (l & 15); if (arow >= 394) arow = 393;
    const __hip_bfloat16* Ap = A + (long)arow * 384 + ((l >> 4) << 3);
    const float* W0 = W + (long)(n0 + (l & 15)) * 384 + ((l >> 4) << 3);
    const long wst = 16L * 384;

    f32x4 acc[4];
    #pragma unroll
    for (int f = 0; f < 4; ++f) acc[f] = f32x4{0.f,0.f,0.f,0.f};
    #pragma unroll 4
    for (int kt = 0; kt < 12; ++kt) {
        int k = kt << 5;
        short8b a  = *reinterpret_cast<const short8b*>(Ap + k);
        short8b b0 = ldw8(W0 + k);
        short8b b1 = ldw8(W0 + wst + k);
        short8b b2 = ldw8(W0 + 2*wst + k);
        short8b b3 = ldw8(W0 + 3*wst + k);
        acc[0] = __builtin_amdgcn_mfma_f32_16x16x32_bf16(a, b0, acc[0], 0, 0, 0);
        acc[1] = __builtin_amdgcn_mfma_f32_16x16x32_bf16(a, b1, acc[1], 0, 0, 0);
        acc[2] = __builtin_amdgcn_mfma_f32_16x16x32_bf16(a, b2, acc[2], 0, 0, 0);
        acc[3] = __builtin_amdgcn_mfma_f32_16x16x32_bf16(a, b3, acc[3], 0, 0, 0);
    }

    int cl = l & 15;
    int rbase = m0 + ((l >> 4) << 2);
    #pragma unroll
    for (int f = 0; f < 4; ++f) {
        int n = n0 + f*16 + cl;
        float bv = bias[n];
        #pragma unroll
        for (int r = 0; r < 4; ++r) {
            int m = rbase + r;
            if (m < 394)
                x[(long)m*384 + n] += acc[f][r] + bv;
        }
    }
}

// ---------------------------------------------------------------------------
// fc2: 2-wave split-K (validated R16), W f32 direct, LDS combine,
// +bias+residual. grid (25,6), 128 threads.
// ---------------------------------------------------------------------------
__global__ __launch_bounds__(128) void fc2_2w_k(
    const __hip_bfloat16* __restrict__ A, const float* __restrict__ W,
    const float* __restrict__ bias, float* __restrict__ x)
{
    __shared__ __align__(16) f32x4 part[4][64];
    int tid = threadIdx.x, w = tid >> 6, l = tid & 63;
    int m0 = blockIdx.x * 16, n0 = blockIdx.y * 64;
    int ks = w * 768;

    int arow = m0 + (l & 15); if (arow >= 394) arow = 393;
    const __hip_bfloat16* Ap = A + (long)arow * 1536 + ks + ((l >> 4) << 3);
    const float* W0 = W + (long)(n0 + (l & 15)) * 1536 + ks + ((l >> 4) << 3);
    const long wst = 16L * 1536;

    f32x4 acc[4];
    #pragma unroll
    for (int f = 0; f < 4; ++f) acc[f] = f32x4{0.f,0.f,0.f,0.f};
    #pragma unroll 4
    for (int kt = 0; kt < 24; ++kt) {
        int k = kt << 5;
        short8b a  = *reinterpret_cast<const short8b*>(Ap + k);
        short8b b0 = ldw8(W0 + k);
        short8b b1 = ldw8(W0 + wst + k);
        short8b b2 = ldw8(W0 + 2*wst + k);
        short8b b3 = ldw8(W0 + 3*wst + k);
        acc[0] = __builtin_amdgcn_mfma_f32_16x16x32_bf16(a, b0, acc[0], 0, 0, 0);
        acc[1] = __builtin_amdgcn_mfma_f32_16x16x32_bf16(a, b1, acc[1], 0, 0, 0);
        acc[2] = __builtin_amdgcn_mfma_f32_16x16x32_bf16(a, b2, acc[2], 0, 0, 0);
        acc[3] = __builtin_amdgcn_mfma_f32_16x16x32_bf16(a, b3, acc[3], 0, 0, 0);
    }

    if (w == 1) {
        #pragma unroll
        for (int f = 0; f < 4; ++f) part[f][l] = acc[f];
    }
    __syncthreads();
    if (w == 0) {
        int cl = l & 15;
        int rbase = m0 + ((l >> 4) << 2);
        #pragma unroll
        for (int f = 0; f < 4; ++f) {
            f32x4 p = part[f][l];
            int n = n0 + f*16 + cl;
            float bv = bias[n];
            #pragma unroll
            for (int r = 0; r < 4; ++r) {
                int m = rbase + r;
                if (m < 394)
                    x[(long)m*384 + n] += acc[f][r] + p[r] + bv;
            }
        }
    }
}

// ---------------------------------------------------------------------------
// Final LN (cls rows only) + head (validated R8).
// ---------------------------------------------------------------------------
__global__ __launch_bounds__(256) void head_k(
    const float* __restrict__ x, const float* __restrict__ g,
    const float* __restrict__ bg, const float* __restrict__ hw,
    const float* __restrict__ hb, float* __restrict__ out)
{
    __shared__ float xn2[2][384];
    __shared__ float red[8];
    int t = threadIdx.x;
    int b = t >> 7, tt = t & 127;
    const float* xr = x + (long)(b*197)*384;   // cls row of batch b
    float v0 = xr[tt], v1 = xr[tt+128], v2 = xr[tt+256];
    int wid = t >> 6, lane = t & 63;
    float sm = v0+v1+v2, sq = v0*v0+v1*v1+v2*v2;
    for (int off = 32; off; off >>= 1) { sm += __shfl_down(sm, off); sq += __shfl_down(sq, off); }
    if (lane == 0) { red[wid] = sm; red[4+wid] = sq; }
    __syncthreads();
    float s = red[b*2] + red[b*2+1], q = red[4+b*2] + red[4+b*2+1];
    float mean = s * (1.f/384.f);
    float var = q * (1.f/384.f) - mean*mean;
    float rstd = rsqrtf(var + 1e-6f);
    xn2[b][tt]     = fmaf((v0-mean)*rstd, g[tt],     bg[tt]);
    xn2[b][tt+128] = fmaf((v1-mean)*rstd, g[tt+128], bg[tt+128]);
    xn2[b][tt+256] = fmaf((v2-mean)*rstd, g[tt+256], bg[tt+256]);
    __syncthreads();
    if (t < 200) {
        int ob = t / 100, n = blockIdx.x*100 + t % 100;
        const float4* xp = reinterpret_cast<const float4*>(xn2[ob]);
        const float4* wp = reinterpret_cast<const float4*>(hw + (long)n*384);
        float a = hb[n];
        for (int d = 0; d < 96; ++d) {
            float4 xv = xp[d], wv = wp[d];
            a = fmaf(xv.x,wv.x, fmaf(xv.y,wv.y, fmaf(xv.z,wv.z, fmaf(xv.w,wv.w, a))));
        }
        out[ob*1000 + n] = a;
    }
}

// ---------------------------------------------------------------------------
extern "C" void kernel_launch(void* const* d_in, const int* in_sizes, int n_in,
                              void* d_out, int out_size, void* d_ws, size_t ws_size,
                              hipStream_t stream)
{
    const float* img      = (const float*)d_in[0];
    const float* fp_w     = (const float*)d_in[2];
    const float* fp_b     = (const float*)d_in[3];
    const float* ap_in_w  = (const float*)d_in[4];
    const float* ap_in_b  = (const float*)d_in[5];
    const float* ap_out_w = (const float*)d_in[6];
    const float* ap_out_b = (const float*)d_in[7];
    const float* cls_tok  = (const float*)d_in[8];
    const float* pos_emb  = (const float*)d_in[9];
    const float* ln1_g    = (const float*)d_in[10];
    const float* ln1_b    = (const float*)d_in[11];
    const float* qkv_w    = (const float*)d_in[12];
    const float* qkv_b    = (const float*)d_in[13];
    const float* proj_w   = (const float*)d_in[14];
    const float* proj_b   = (const float*)d_in[15];
    const float* ln2_g    = (const float*)d_in[16];
    const float* ln2_b    = (const float*)d_in[17];
    const float* fc1_w    = (const float*)d_in[18];
    const float* fc1_b    = (const float*)d_in[19];
    const float* fc2_w    = (const float*)d_in[20];
    const float* fc2_b    = (const float*)d_in[21];
    const float* norm_g   = (const float*)d_in[22];
    const float* norm_b   = (const float*)d_in[23];
    const float* head_w   = (const float*)d_in[24];
    const float* head_b   = (const float*)d_in[25];
    (void)in_sizes; (void)n_in; (void)out_size; (void)ws_size;
    float* out = (float*)d_out;

    float* ws = (float*)d_ws;
    size_t off = 0;
    auto alloc = [&](size_t nfl) { float* p = ws + off; off += (nfl + 63) & ~(size_t)63; return p; };
    float* W2     = alloc(1152*3);
    float* b2     = alloc(1152);
    float* hGm    = alloc(64);
    float* x      = alloc(394L*384);
    __hip_bfloat16* pooledb = (__hip_bfloat16*)alloc(392L*384/2);
    __hip_bfloat16* attnb   = (__hip_bfloat16*)alloc(394L*384/2 + 64);
    __hip_bfloat16* hbufb   = (__hip_bfloat16*)alloc(394L*1536/2 + 64);
    __hip_bfloat16* qb      = (__hip_bfloat16*)alloc(12L*208*64/2);
    __hip_bfloat16* kb      = (__hip_bfloat16*)alloc(12L*208*64/2);
    __hip_bfloat16* vT      = (__hip_bfloat16*)alloc(12L*64*224/2);

    // ---- setup: vT pad + W2/b2 prep + x cls rows (one small dispatch) ----
    prep_all_k<<<86, 256, 0, stream>>>(vT, ap_in_w, ap_in_b, fp_w, fp_b,
                                       cls_tok, pos_emb, W2, b2, x);

    // ---- tokenizer ----
    prep_head_k<<<4, 64, 0, stream>>>(W2, b2, hGm);
    tok_attn_k<<<dim3(196,4,2), 1024, 0, stream>>>(img, hGm, W2, b2, pooledb);
    outproj_x_k<<<dim3(25,6), 64, 0, stream>>>(pooledb, ap_out_w, ap_out_b, pos_emb, x);

    // ---- ViT trunk (5 dispatches per layer, f32 weights direct) ----
    for (int i = 0; i < 12; ++i) {
        ln_gemm_k<1><<<dim3(25,18), 64, 0, stream>>>(
            x, ln1_g + i*384, ln1_b + i*384, qkv_w + (long)i*1152*384,
            qkv_b + i*1152, qb, kb, vT, 394, 1152);
        attn_flash_k<<<dim3(13,12), 64, 0, stream>>>(qb, kb, vT, attnb);
        proj_k<<<dim3(25,6), 64, 0, stream>>>(
            attnb, proj_w + (long)i*384*384, proj_b + i*384, x);
        ln_gemm_k<2><<<dim3(25,24), 64, 0, stream>>>(
            x, ln2_g + i*384, ln2_b + i*384, fc1_w + (long)i*1536*384,
            fc1_b + i*1536, hbufb, nullptr, nullptr, 394, 1536);
        fc2_2w_k<<<dim3(25,6), 128, 0, stream>>>(
            hbufb, fc2_w + (long)i*384*1536, fc2_b + i*384, x);
    }

    // ---- head ----
    head_k<<<10, 256, 0, stream>>>(x, norm_g, norm_b, head_w, head_b, out);
}

// Round 18
// 812.766 us; speedup vs baseline: 1.3998x; 1.3998x over previous
//
#include <hip/hip_runtime.h>
#include <hip/hip_bf16.h>
#include <math.h>

// ---------------------------------------------------------------------------
// Model dims: B=2, Cn=3, HI=WI=224, S=196, P=256, D=384, H_TOK=4
// DEPTH=12, H_VIT=6 (dh=64), HID=1536, NCLS=1000
// x layout: [394][384] f32 (rows 0,197 = cls).
// R18 = exact revert to R16 (816 us best): cvt pre-pass at full parallelism
// beats f32-direct weight loads in low-occupancy GEMMs (R17: +320 us).
// ---------------------------------------------------------------------------

typedef __attribute__((ext_vector_type(8))) short short8b;
typedef __attribute__((ext_vector_type(4))) float f32x4;

static __device__ __forceinline__ float gelu_exact(float v) {
    return 0.5f * v * (1.0f + erff(v * 0.70710678118654752440f));
}
static __device__ __forceinline__ short bf16s(float f) {
    __hip_bfloat16 h = __float2bfloat16(f);
    return *reinterpret_cast<short*>(&h);
}

// ---------------------------------------------------------------------------
// Setup: convert 5 weight groups f32->bf16, grid-stride (2048 blocks),
// zero vT key pad, AND (5 tail blocks, co-resident) prep W2/b2 + x cls rows.
// ---------------------------------------------------------------------------
#define CVTB 2048
__global__ __launch_bounds__(256) void cvt_all_k(
    const float* __restrict__ qw, const float* __restrict__ pw,
    const float* __restrict__ f1w, const float* __restrict__ f2w,
    const float* __restrict__ aow,
    __hip_bfloat16* __restrict__ qd, __hip_bfloat16* __restrict__ pd,
    __hip_bfloat16* __restrict__ f1d, __hip_bfloat16* __restrict__ f2d,
    __hip_bfloat16* __restrict__ aod, __hip_bfloat16* __restrict__ vT,
    const float* __restrict__ ap_in_w, const float* __restrict__ ap_in_b,
    const float* __restrict__ fp_w, const float* __restrict__ fp_b,
    const float* __restrict__ cls, const float* __restrict__ pos,
    float* __restrict__ W2, float* __restrict__ b2, float* __restrict__ xs)
{
    if (blockIdx.x >= CVTB) {
        // ---- prep_w2 part (5 blocks, run concurrently with streaming) ----
        int o = (blockIdx.x - CVTB) * 256 + threadIdx.x;
        if (o < 384) {
            float v = cls[o] + pos[o];
            xs[o] = v;
            xs[197*384 + o] = v;
        }
        if (o >= 1152) return;
        const float* ar = ap_in_w + (long)o * 384;
        float a0 = 0.f, a1 = 0.f, a2 = 0.f, ab = ap_in_b[o];
        for (int d = 0; d < 384; ++d) {
            float aw = ar[d];
            a0 = fmaf(aw, fp_w[d*3+0], a0);
            a1 = fmaf(aw, fp_w[d*3+1], a1);
            a2 = fmaf(aw, fp_w[d*3+2], a2);
            ab = fmaf(aw, fp_b[d], ab);
        }
        W2[o*3+0] = a0; W2[o*3+1] = a1; W2[o*3+2] = a2; b2[o] = ab;
        return;
    }
    const long N1 = 5308416, N2 = 1769472, N3 = 7077888, N4 = 147456;
    const long NCH = (N1 + N2 + 2*N3 + N4) / 16;   // 1336320 chunks
    long t0 = (long)blockIdx.x*256 + threadIdx.x;
    // vT key-pad zero (once, using first-iteration id)
    if (t0 < 12*64*27) {
        int c = (int)(t0 % 27), r = (int)(t0 / 27);
        vT[(long)r*224 + 197 + c] = __float2bfloat16(0.f);
    }
    for (long t = t0; t < NCH; t += (long)CVTB*256) {
        long idx = t * 16;
        const float* src; __hip_bfloat16* dst; long off;
        if (idx < N1)                { src=qw;  dst=qd;  off=idx; }
        else if (idx < N1+N2)        { src=pw;  dst=pd;  off=idx-N1; }
        else if (idx < N1+N2+N3)     { src=f1w; dst=f1d; off=idx-N1-N2; }
        else if (idx < N1+N2+2*N3)   { src=f2w; dst=f2d; off=idx-N1-N2-N3; }
        else                         { src=aow; dst=aod; off=idx-N1-N2-2*N3; }
        float4 v0 = *reinterpret_cast<const float4*>(src + off);
        float4 v1 = *reinterpret_cast<const float4*>(src + off + 4);
        float4 v2 = *reinterpret_cast<const float4*>(src + off + 8);
        float4 v3 = *reinterpret_cast<const float4*>(src + off + 12);
        short8b o0, o1;
        o0[0]=bf16s(v0.x); o0[1]=bf16s(v0.y); o0[2]=bf16s(v0.z); o0[3]=bf16s(v0.w);
        o0[4]=bf16s(v1.x); o0[5]=bf16s(v1.y); o0[6]=bf16s(v1.z); o0[7]=bf16s(v1.w);
        o1[0]=bf16s(v2.x); o1[1]=bf16s(v2.y); o1[2]=bf16s(v2.z); o1[3]=bf16s(v2.w);
        o1[4]=bf16s(v3.x); o1[5]=bf16s(v3.y); o1[6]=bf16s(v3.z); o1[7]=bf16s(v3.w);
        *reinterpret_cast<short8b*>(dst + off)     = o0;
        *reinterpret_cast<short8b*>(dst + off + 8) = o1;
    }
}

// ---------------------------------------------------------------------------
__global__ __launch_bounds__(64) void prep_head_k(
    const float* __restrict__ W2, const float* __restrict__ b2,
    float* __restrict__ hGm)
{
    int h = blockIdx.x;
    int lane = threadIdx.x;
    float G00=0,G01=0,G02=0,G10=0,G11=0,G12=0,G20=0,G21=0,G22=0;
    float u0=0,u1=0,u2=0,w0=0,w1=0,w2=0,c0=0;
    for (int d = lane; d < 96; d += 64) {
        int oq = h*96 + d, ok = 384 + h*96 + d;
        float q0=W2[oq*3],q1=W2[oq*3+1],q2=W2[oq*3+2];
        float k0=W2[ok*3],k1=W2[ok*3+1],k2=W2[ok*3+2];
        float bq=b2[oq], bk=b2[ok];
        G00=fmaf(q0,k0,G00); G01=fmaf(q0,k1,G01); G02=fmaf(q0,k2,G02);
        G10=fmaf(q1,k0,G10); G11=fmaf(q1,k1,G11); G12=fmaf(q1,k2,G12);
        G20=fmaf(q2,k0,G20); G21=fmaf(q2,k1,G21); G22=fmaf(q2,k2,G22);
        u0=fmaf(q0,bk,u0); u1=fmaf(q1,bk,u1); u2=fmaf(q2,bk,u2);
        w0=fmaf(k0,bq,w0); w1=fmaf(k1,bq,w1); w2=fmaf(k2,bq,w2);
        c0=fmaf(bq,bk,c0);
    }
    float vals[16] = {G00,G01,G02,u0, G10,G11,G12,u1, G20,G21,G22,u2, w0,w1,w2,c0};
    const float sc = 0.10206207261596577f; // 1/sqrt(96)
    #pragma unroll
    for (int q = 0; q < 16; ++q) {
        float v = vals[q];
        for (int off = 32; off; off >>= 1) v += __shfl_down(v, off);
        if (lane == 0) hGm[h*16 + q] = v * sc;
    }
}

// ---------------------------------------------------------------------------
// Tokenizer attention, 1-pass, 1024 threads, interleaved j-split
// (validated R14-R16: conflict-free).
// ---------------------------------------------------------------------------
__global__ __launch_bounds__(1024) void tok_attn_k(
    const float* __restrict__ img, const float* __restrict__ hGm,
    const float* __restrict__ W2, const float* __restrict__ b2,
    __hip_bfloat16* __restrict__ pooledb)
{
    int s = blockIdx.x, h = blockIdx.y, b = blockIdx.z;
    int tid = threadIdx.x;
    __shared__ float4 pxm[256];
    __shared__ float4 ylds[256];
    __shared__ float  tsum[3];

    if (tid < 256) {
        int gy = s / 14, gx = s - gy*14;
        int row = gy*16 + (tid >> 4), col = gx*16 + (tid & 15);
        long base = ((long)b*3*224 + row)*224 + col;
        float p0 = img[base];
        float p1 = img[base + 224*224];
        float p2 = img[base + 2*224*224];
        const float4* M4 = reinterpret_cast<const float4*>(hGm) + h*4;
        float4 r0 = M4[0], r1 = M4[1], r2 = M4[2], r3 = M4[3];
        float y0 = fmaf(p0,r0.x, fmaf(p1,r0.y, fmaf(p2,r0.z, r0.w)));
        float y1 = fmaf(p0,r1.x, fmaf(p1,r1.y, fmaf(p2,r1.z, r1.w)));
        float y2 = fmaf(p0,r2.x, fmaf(p1,r2.y, fmaf(p2,r2.z, r2.w)));
        float y3 = fmaf(p0,r3.x, fmaf(p1,r3.y, fmaf(p2,r3.z, r3.w)));
        ylds[tid] = make_float4(y0,y1,y2,y3);
        pxm[tid]  = make_float4(p0,p1,p2,0.f);
    }
    __syncthreads();

    int i = tid >> 2, sub = tid & 3;
    float4 P = pxm[i];
    float li = 0.f, w0 = 0.f, w1 = 0.f, w2 = 0.f;
    #pragma unroll 4
    for (int jj = 0; jj < 64; ++jj) {
        int j = jj*4 + sub;
        float4 Y = ylds[j];
        float4 q = pxm[j];
        float scr = fmaf(P.x,Y.x, fmaf(P.y,Y.y, fmaf(P.z,Y.z, Y.w)));
        float e = __expf(scr);
        li += e;
        w0 = fmaf(e, q.x, w0);
        w1 = fmaf(e, q.y, w1);
        w2 = fmaf(e, q.z, w2);
    }
    li += __shfl_xor(li, 1); li += __shfl_xor(li, 2);
    w0 += __shfl_xor(w0, 1); w0 += __shfl_xor(w0, 2);
    w1 += __shfl_xor(w1, 1); w1 += __shfl_xor(w1, 2);
    w2 += __shfl_xor(w2, 1); w2 += __shfl_xor(w2, 2);
    float rl = 1.f / li;
    __syncthreads();
    if (sub == 0) pxm[i] = make_float4(w0*rl, w1*rl, w2*rl, 0.f);
    __syncthreads();

    int w = tid >> 6, lane = tid & 63;
    if (w < 3) {
        float prt = 0.f;
        for (int j = lane; j < 256; j += 64)
            prt += reinterpret_cast<const float*>(&pxm[j])[w];
        for (int off = 32; off; off >>= 1) prt += __shfl_down(prt, off);
        if (lane == 0) tsum[w] = prt;
    }
    __syncthreads();

    if (tid < 96) {
        int o = 768 + h*96 + tid;
        float v = (W2[o*3]*tsum[0] + W2[o*3+1]*tsum[1] + W2[o*3+2]*tsum[2]) * (1.f/256.f)
                  + b2[o];
        pooledb[((long)(b*196 + s))*384 + h*96 + tid] = __float2bfloat16(v);
    }
}

// ---------------------------------------------------------------------------
// Tokenizer out-proj -> x directly, pos-embed fused.
// ---------------------------------------------------------------------------
__global__ __launch_bounds__(64) void outproj_x_k(
    const __hip_bfloat16* __restrict__ A, const __hip_bfloat16* __restrict__ W,
    const float* __restrict__ bias, const float* __restrict__ pos,
    float* __restrict__ xs)
{
    int l = threadIdx.x;
    int m0 = blockIdx.x * 16, n0 = blockIdx.y * 64;
    int arow = m0 + (l & 15); if (arow >= 392) arow = 391;
    const __hip_bfloat16* Ap = A + (long)arow * 384 + ((l >> 4) << 3);
    const __hip_bfloat16* W0 = W + (long)(n0 + (l & 15)) * 384 + ((l >> 4) << 3);

    f32x4 acc[4];
    #pragma unroll
    for (int f = 0; f < 4; ++f) acc[f] = f32x4{0.f,0.f,0.f,0.f};
    #pragma unroll 4
    for (int kt = 0; kt < 12; ++kt) {
        int k = kt << 5;
        short8b a  = *reinterpret_cast<const short8b*>(Ap + k);
        short8b b0 = *reinterpret_cast<const short8b*>(W0 + k);
        short8b b1 = *reinterpret_cast<const short8b*>(W0 + 16L*384 + k);
        short8b b2 = *reinterpret_cast<const short8b*>(W0 + 32L*384 + k);
        short8b b3 = *reinterpret_cast<const short8b*>(W0 + 48L*384 + k);
        acc[0] = __builtin_amdgcn_mfma_f32_16x16x32_bf16(a, b0, acc[0], 0, 0, 0);
        acc[1] = __builtin_amdgcn_mfma_f32_16x16x32_bf16(a, b1, acc[1], 0, 0, 0);
        acc[2] = __builtin_amdgcn_mfma_f32_16x16x32_bf16(a, b2, acc[2], 0, 0, 0);
        acc[3] = __builtin_amdgcn_mfma_f32_16x16x32_bf16(a, b3, acc[3], 0, 0, 0);
    }

    int cl = l & 15;
    int rbase = m0 + ((l >> 4) << 2);
    #pragma unroll
    for (int f = 0; f < 4; ++f) {
        int n = n0 + f*16 + cl;
        float bv = bias[n];
        #pragma unroll
        for (int r = 0; r < 4; ++r) {
            int m = rbase + r;
            if (m >= 392) continue;
            int b = m / 196;
            int srow = m - 196*b + 1;
            xs[(long)(m + b + 1)*384 + n] = acc[f][r] + bv + pos[(long)srow*384 + n];
        }
    }
}

// ---------------------------------------------------------------------------
// Fused LayerNorm + MFMA GEMM (K=384). Validated R3/R8.
// EPI=1: qkv scatter to qb/kb (x0.125 on q) /vT.  EPI=2: gelu -> bf16 C.
// ---------------------------------------------------------------------------
template<int EPI>
__global__ __launch_bounds__(64) void ln_gemm_k(
    const float* __restrict__ x, const float* __restrict__ g,
    const float* __restrict__ b, const __hip_bfloat16* __restrict__ W,
    const float* __restrict__ bias,
    __hip_bfloat16* __restrict__ o0, __hip_bfloat16* __restrict__ o1,
    __hip_bfloat16* __restrict__ o2, int M, int N)
{
    int l = threadIdx.x;
    int m0 = blockIdx.x * 16, n0 = blockIdx.y * 64;
    int cl = l & 15, hi = l >> 4;
    int row = m0 + cl; if (row >= M) row = M - 1;
    const float* xp = x + (long)row*384 + (hi << 3);

    float sum = 0.f, sq = 0.f;
    #pragma unroll
    for (int t = 0; t < 12; ++t) {
        float4 v0 = *reinterpret_cast<const float4*>(xp + t*32);
        float4 v1 = *reinterpret_cast<const float4*>(xp + t*32 + 4);
        sum += v0.x+v0.y+v0.z+v0.w + v1.x+v1.y+v1.z+v1.w;
        sq  += v0.x*v0.x+v0.y*v0.y+v0.z*v0.z+v0.w*v0.w
             + v1.x*v1.x+v1.y*v1.y+v1.z*v1.z+v1.w*v1.w;
    }
    sum += __shfl_xor(sum, 16); sum += __shfl_xor(sum, 32);
    sq  += __shfl_xor(sq, 16);  sq  += __shfl_xor(sq, 32);
    float mean = sum * (1.f/384.f);
    float var  = sq * (1.f/384.f) - mean*mean;
    float rstd = rsqrtf(var + 1e-6f);

    const __hip_bfloat16* Wp = W + (long)(n0 + cl)*384 + (hi << 3);
    f32x4 acc[4];
    #pragma unroll
    for (int f = 0; f < 4; ++f) acc[f] = f32x4{0.f,0.f,0.f,0.f};

    #pragma unroll 2
    for (int t = 0; t < 12; ++t) {
        int k = t*32 + (hi << 3);
        float4 v0 = *reinterpret_cast<const float4*>(xp + t*32);
        float4 v1 = *reinterpret_cast<const float4*>(xp + t*32 + 4);
        float4 g0 = *reinterpret_cast<const float4*>(g + k);
        float4 g1 = *reinterpret_cast<const float4*>(g + k + 4);
        float4 bb0 = *reinterpret_cast<const float4*>(b + k);
        float4 bb1 = *reinterpret_cast<const float4*>(b + k + 4);
        short8b a;
        a[0] = bf16s(fmaf((v0.x-mean)*rstd, g0.x, bb0.x));
        a[1] = bf16s(fmaf((v0.y-mean)*rstd, g0.y, bb0.y));
        a[2] = bf16s(fmaf((v0.z-mean)*rstd, g0.z, bb0.z));
        a[3] = bf16s(fmaf((v0.w-mean)*rstd, g0.w, bb0.w));
        a[4] = bf16s(fmaf((v1.x-mean)*rstd, g1.x, bb1.x));
        a[5] = bf16s(fmaf((v1.y-mean)*rstd, g1.y, bb1.y));
        a[6] = bf16s(fmaf((v1.z-mean)*rstd, g1.z, bb1.z));
        a[7] = bf16s(fmaf((v1.w-mean)*rstd, g1.w, bb1.w));
        short8b w0 = *reinterpret_cast<const short8b*>(Wp + t*32);
        short8b w1 = *reinterpret_cast<const short8b*>(Wp + 16L*384 + t*32);
        short8b w2 = *reinterpret_cast<const short8b*>(Wp + 32L*384 + t*32);
        short8b w3 = *reinterpret_cast<const short8b*>(Wp + 48L*384 + t*32);
        acc[0] = __builtin_amdgcn_mfma_f32_16x16x32_bf16(a, w0, acc[0], 0, 0, 0);
        acc[1] = __builtin_amdgcn_mfma_f32_16x16x32_bf16(a, w1, acc[1], 0, 0, 0);
        acc[2] = __builtin_amdgcn_mfma_f32_16x16x32_bf16(a, w2, acc[2], 0, 0, 0);
        acc[3] = __builtin_amdgcn_mfma_f32_16x16x32_bf16(a, w3, acc[3], 0, 0, 0);
    }

    int rb = hi << 2;
    #pragma unroll
    for (int f = 0; f < 4; ++f) {
        int n = n0 + f*16 + cl;
        float bv = bias[n];
        #pragma unroll
        for (int r = 0; r < 4; ++r) {
            int m = m0 + rb + r;
            if (m >= M) continue;
            float v = acc[f][r] + bv;
            if (EPI == 1) {
                int bb = (m >= 197) ? 1 : 0;
                int tokr = m - bb*197;
                if (n < 384) {
                    int h = n >> 6, ch = n & 63;
                    o0[((long)(bb*6 + h)*208 + tokr)*64 + ch] = __float2bfloat16(v * 0.125f);
                } else if (n < 768) {
                    int nn = n - 384, h = nn >> 6, ch = nn & 63;
                    o1[((long)(bb*6 + h)*208 + tokr)*64 + ch] = __float2bfloat16(v);
                } else {
                    int nn = n - 768, h = nn >> 6, ch = nn & 63;
                    o2[((long)(bb*6 + h)*64 + ch)*224 + tokr] = __float2bfloat16(v);
                }
            } else { // EPI == 2
                o0[(long)m*N + n] = __float2bfloat16(gelu_exact(v));
            }
        }
    }
}

// ---------------------------------------------------------------------------
// Fused flash attention (validated R3/R8). grid (13 qt, 12 bh), 1 wave.
// ---------------------------------------------------------------------------
__global__ __launch_bounds__(64) void attn_flash_k(
    const __hip_bfloat16* __restrict__ qb, const __hip_bfloat16* __restrict__ kb,
    const __hip_bfloat16* __restrict__ vT, __hip_bfloat16* __restrict__ attnb)
{
    __shared__ __align__(16) short lp[16*232];
    int l = threadIdx.x;
    int qt = blockIdx.x, bh = blockIdx.y;
    int q0 = qt * 16;
    int cl = l & 15, hi = l >> 4;

    if (l < 32) {
        int row = l >> 1, hf = l & 1;
        *reinterpret_cast<int4*>(lp + row*232 + 208 + hf*8) = int4{0,0,0,0};
    }

    const __hip_bfloat16* Qp = qb + ((long)bh*208 + q0 + cl)*64 + (hi << 3);
    const __hip_bfloat16* Kp = kb + ((long)bh*208 + cl)*64 + (hi << 3);
    f32x4 s[13];
    #pragma unroll
    for (int f = 0; f < 13; ++f) s[f] = f32x4{0.f,0.f,0.f,0.f};
    #pragma unroll
    for (int kt = 0; kt < 2; ++kt) {
        short8b a = *reinterpret_cast<const short8b*>(Qp + kt*32);
        #pragma unroll
        for (int f = 0; f < 13; ++f) {
            short8b kk = *reinterpret_cast<const short8b*>(Kp + (long)f*16*64 + kt*32);
            s[f] = __builtin_amdgcn_mfma_f32_16x16x32_bf16(a, kk, s[f], 0, 0, 0);
        }
    }
    if (cl >= 5) s[12] = f32x4{-1e30f,-1e30f,-1e30f,-1e30f};

    #pragma unroll
    for (int r = 0; r < 4; ++r) {
        float m = s[0][r];
        #pragma unroll
        for (int f = 1; f < 13; ++f) m = fmaxf(m, s[f][r]);
        m = fmaxf(m, __shfl_xor(m, 1));
        m = fmaxf(m, __shfl_xor(m, 2));
        m = fmaxf(m, __shfl_xor(m, 4));
        m = fmaxf(m, __shfl_xor(m, 8));
        float e[13]; float ssum = 0.f;
        #pragma unroll
        for (int f = 0; f < 13; ++f) { e[f] = __expf(s[f][r] - m); ssum += e[f]; }
        ssum += __shfl_xor(ssum, 1);
        ssum += __shfl_xor(ssum, 2);
        ssum += __shfl_xor(ssum, 4);
        ssum += __shfl_xor(ssum, 8);
        float ri = 1.f / ssum;
        int prow = (hi << 2) + r;
        #pragma unroll
        for (int f = 0; f < 13; ++f)
            lp[prow*232 + f*16 + cl] = bf16s(e[f] * ri);
    }
    __syncthreads();

    f32x4 o[4];
    #pragma unroll
    for (int f = 0; f < 4; ++f) o[f] = f32x4{0.f,0.f,0.f,0.f};
    const __hip_bfloat16* Vp = vT + ((long)bh*64 + cl)*224 + (hi << 3);
    #pragma unroll
    for (int kt = 0; kt < 7; ++kt) {
        short8b pa = *reinterpret_cast<const short8b*>(&lp[cl*232 + (hi << 3) + kt*32]);
        #pragma unroll
        for (int f2 = 0; f2 < 4; ++f2) {
            short8b vb = *reinterpret_cast<const short8b*>(Vp + (long)f2*16*224 + kt*32);
            o[f2] = __builtin_amdgcn_mfma_f32_16x16x32_bf16(pa, vb, o[f2], 0, 0, 0);
        }
    }

    int b = bh / 6, h = bh - b*6;
    #pragma unroll
    for (int f2 = 0; f2 < 4; ++f2) {
        int ch = h*64 + f2*16 + cl;
        #pragma unroll
        for (int r = 0; r < 4; ++r) {
            int qr = q0 + (hi << 2) + r;
            if (qr < 197)
                attnb[((long)(b*197 + qr))*384 + ch] = __float2bfloat16(o[f2][r]);
        }
    }
}

// ---------------------------------------------------------------------------
// MFMA bf16 GEMM, 1 wave/block, 16x64 tile (proj). Validated R2/R3/R8.
// ---------------------------------------------------------------------------
template<bool GEL, bool RES, bool OBF>
__global__ __launch_bounds__(64) void gemm_mfma_k(
    const __hip_bfloat16* __restrict__ A, const __hip_bfloat16* __restrict__ W,
    const float* __restrict__ bias, const float* __restrict__ resid,
    void* __restrict__ Cv, int M, int N, int K, int lda, int ldw, int ldc,
    int kpart, long sC)
{
    int l = threadIdx.x;
    int m0 = blockIdx.x * 16, n0 = blockIdx.y * 64;
    int z = blockIdx.z;
    int ks = z * kpart;
    int klen = K - ks; if (klen > kpart) klen = kpart;

    int arow = m0 + (l & 15); if (arow >= M) arow = M - 1;
    const __hip_bfloat16* Ap = A + (long)arow * lda + ks + ((l >> 4) << 3);
    const __hip_bfloat16* W0 = W + (long)(n0 + (l & 15)) * ldw + ks + ((l >> 4) << 3);
    long wst = (long)ldw * 16;

    f32x4 acc[4];
    #pragma unroll
    for (int f = 0; f < 4; ++f) acc[f] = f32x4{0.f,0.f,0.f,0.f};

    int niter = klen >> 5;
    #pragma unroll 4
    for (int kt = 0; kt < niter; ++kt) {
        int k = kt << 5;
        short8b a  = *reinterpret_cast<const short8b*>(Ap + k);
        short8b b0 = *reinterpret_cast<const short8b*>(W0 + k);
        short8b b1 = *reinterpret_cast<const short8b*>(W0 + wst + k);
        short8b b2 = *reinterpret_cast<const short8b*>(W0 + 2*wst + k);
        short8b b3 = *reinterpret_cast<const short8b*>(W0 + 3*wst + k);
        acc[0] = __builtin_amdgcn_mfma_f32_16x16x32_bf16(a, b0, acc[0], 0, 0, 0);
        acc[1] = __builtin_amdgcn_mfma_f32_16x16x32_bf16(a, b1, acc[1], 0, 0, 0);
        acc[2] = __builtin_amdgcn_mfma_f32_16x16x32_bf16(a, b2, acc[2], 0, 0, 0);
        acc[3] = __builtin_amdgcn_mfma_f32_16x16x32_bf16(a, b3, acc[3], 0, 0, 0);
    }

    int cl = l & 15;
    int rbase = m0 + ((l >> 4) << 2);
    float* Cf = (float*)Cv + z * sC;
    __hip_bfloat16* Cb = (__hip_bfloat16*)Cv;
    #pragma unroll
    for (int f = 0; f < 4; ++f) {
        int n = n0 + f*16 + cl;
        float bv = bias ? bias[n] : 0.f;
        #pragma unroll
        for (int r = 0; r < 4; ++r) {
            int m = rbase + r;
            if (m >= M) continue;
            float v = acc[f][r] + bv;
            if (GEL) v = gelu_exact(v);
            if (RES) v += resid[(long)m*ldc + n];
            if (OBF) Cb[(long)m*ldc + n] = __float2bfloat16(v);
            else     Cf[(long)m*ldc + n] = v;
        }
    }
}

// ---------------------------------------------------------------------------
// fc2: 2-wave split-K (wave w handles K-half w), LDS combine, +bias+residual.
// grid (25,6), 128 threads. Validated R16 (+90 us total win).
// ---------------------------------------------------------------------------
__global__ __launch_bounds__(128) void fc2_2w_k(
    const __hip_bfloat16* __restrict__ A, const __hip_bfloat16* __restrict__ W,
    const float* __restrict__ bias, float* __restrict__ x)
{
    __shared__ __align__(16) f32x4 part[4][64];
    int tid = threadIdx.x, w = tid >> 6, l = tid & 63;
    int m0 = blockIdx.x * 16, n0 = blockIdx.y * 64;
    int ks = w * 768;

    int arow = m0 + (l & 15); if (arow >= 394) arow = 393;
    const __hip_bfloat16* Ap = A + (long)arow * 1536 + ks + ((l >> 4) << 3);
    const __hip_bfloat16* W0 = W + (long)(n0 + (l & 15)) * 1536 + ks + ((l >> 4) << 3);
    const long wst = 16L * 1536;

    f32x4 acc[4];
    #pragma unroll
    for (int f = 0; f < 4; ++f) acc[f] = f32x4{0.f,0.f,0.f,0.f};
    #pragma unroll 4
    for (int kt = 0; kt < 24; ++kt) {
        int k = kt << 5;
        short8b a  = *reinterpret_cast<const short8b*>(Ap + k);
        short8b b0 = *reinterpret_cast<const short8b*>(W0 + k);
        short8b b1 = *reinterpret_cast<const short8b*>(W0 + wst + k);
        short8b b2 = *reinterpret_cast<const short8b*>(W0 + 2*wst + k);
        short8b b3 = *reinterpret_cast<const short8b*>(W0 + 3*wst + k);
        acc[0] = __builtin_amdgcn_mfma_f32_16x16x32_bf16(a, b0, acc[0], 0, 0, 0);
        acc[1] = __builtin_amdgcn_mfma_f32_16x16x32_bf16(a, b1, acc[1], 0, 0, 0);
        acc[2] = __builtin_amdgcn_mfma_f32_16x16x32_bf16(a, b2, acc[2], 0, 0, 0);
        acc[3] = __builtin_amdgcn_mfma_f32_16x16x32_bf16(a, b3, acc[3], 0, 0, 0);
    }

    if (w == 1) {
        #pragma unroll
        for (int f = 0; f < 4; ++f) part[f][l] = acc[f];
    }
    __syncthreads();
    if (w == 0) {
        int cl = l & 15;
        int rbase = m0 + ((l >> 4) << 2);
        #pragma unroll
        for (int f = 0; f < 4; ++f) {
            f32x4 p = part[f][l];
            int n = n0 + f*16 + cl;
            float bv = bias[n];
            #pragma unroll
            for (int r = 0; r < 4; ++r) {
                int m = rbase + r;
                if (m < 394)
                    x[(long)m*384 + n] += acc[f][r] + p[r] + bv;
            }
        }
    }
}

// ---------------------------------------------------------------------------
// Final LN (cls rows only) + head (validated R8).
// ---------------------------------------------------------------------------
__global__ __launch_bounds__(256) void head_k(
    const float* __restrict__ x, const float* __restrict__ g,
    const float* __restrict__ bg, const float* __restrict__ hw,
    const float* __restrict__ hb, float* __restrict__ out)
{
    __shared__ float xn2[2][384];
    __shared__ float red[8];
    int t = threadIdx.x;
    int b = t >> 7, tt = t & 127;
    const float* xr = x + (long)(b*197)*384;   // cls row of batch b
    float v0 = xr[tt], v1 = xr[tt+128], v2 = xr[tt+256];
    int wid = t >> 6, lane = t & 63;
    float sm = v0+v1+v2, sq = v0*v0+v1*v1+v2*v2;
    for (int off = 32; off; off >>= 1) { sm += __shfl_down(sm, off); sq += __shfl_down(sq, off); }
    if (lane == 0) { red[wid] = sm; red[4+wid] = sq; }
    __syncthreads();
    float s = red[b*2] + red[b*2+1], q = red[4+b*2] + red[4+b*2+1];
    float mean = s * (1.f/384.f);
    float var = q * (1.f/384.f) - mean*mean;
    float rstd = rsqrtf(var + 1e-6f);
    xn2[b][tt]     = fmaf((v0-mean)*rstd, g[tt],     bg[tt]);
    xn2[b][tt+128] = fmaf((v1-mean)*rstd, g[tt+128], bg[tt+128]);
    xn2[b][tt+256] = fmaf((v2-mean)*rstd, g[tt+256], bg[tt+256]);
    __syncthreads();
    if (t < 200) {
        int ob = t / 100, n = blockIdx.x*100 + t % 100;
        const float4* xp = reinterpret_cast<const float4*>(xn2[ob]);
        const float4* wp = reinterpret_cast<const float4*>(hw + (long)n*384);
        float a = hb[n];
        for (int d = 0; d < 96; ++d) {
            float4 xv = xp[d], wv = wp[d];
            a = fmaf(xv.x,wv.x, fmaf(xv.y,wv.y, fmaf(xv.z,wv.z, fmaf(xv.w,wv.w, a))));
        }
        out[ob*1000 + n] = a;
    }
}

// ---------------------------------------------------------------------------
extern "C" void kernel_launch(void* const* d_in, const int* in_sizes, int n_in,
                              void* d_out, int out_size, void* d_ws, size_t ws_size,
                              hipStream_t stream)
{
    const float* img      = (const float*)d_in[0];
    const float* fp_w     = (const float*)d_in[2];
    const float* fp_b     = (const float*)d_in[3];
    const float* ap_in_w  = (const float*)d_in[4];
    const float* ap_in_b  = (const float*)d_in[5];
    const float* ap_out_w = (const float*)d_in[6];
    const float* ap_out_b = (const float*)d_in[7];
    const float* cls_tok  = (const float*)d_in[8];
    const float* pos_emb  = (const float*)d_in[9];
    const float* ln1_g    = (const float*)d_in[10];
    const float* ln1_b    = (const float*)d_in[11];
    const float* qkv_w    = (const float*)d_in[12];
    const float* qkv_b    = (const float*)d_in[13];
    const float* proj_w   = (const float*)d_in[14];
    const float* proj_b   = (const float*)d_in[15];
    const float* ln2_g    = (const float*)d_in[16];
    const float* ln2_b    = (const float*)d_in[17];
    const float* fc1_w    = (const float*)d_in[18];
    const float* fc1_b    = (const float*)d_in[19];
    const float* fc2_w    = (const float*)d_in[20];
    const float* fc2_b    = (const float*)d_in[21];
    const float* norm_g   = (const float*)d_in[22];
    const float* norm_b   = (const float*)d_in[23];
    const float* head_w   = (const float*)d_in[24];
    const float* head_b   = (const float*)d_in[25];
    (void)in_sizes; (void)n_in; (void)out_size; (void)ws_size;
    float* out = (float*)d_out;

    float* ws = (float*)d_ws;
    size_t off = 0;
    auto alloc = [&](size_t nfl) { float* p = ws + off; off += (nfl + 63) & ~(size_t)63; return p; };
    float* W2     = alloc(1152*3);
    float* b2     = alloc(1152);
    float* hGm    = alloc(64);
    float* x      = alloc(394L*384);
    __hip_bfloat16* pooledb = (__hip_bfloat16*)alloc(392L*384/2);
    __hip_bfloat16* attnb   = (__hip_bfloat16*)alloc(394L*384/2 + 64);
    __hip_bfloat16* hbufb   = (__hip_bfloat16*)alloc(394L*1536/2 + 64);
    __hip_bfloat16* qb      = (__hip_bfloat16*)alloc(12L*208*64/2);
    __hip_bfloat16* kb      = (__hip_bfloat16*)alloc(12L*208*64/2);
    __hip_bfloat16* vT      = (__hip_bfloat16*)alloc(12L*64*224/2);
    __hip_bfloat16* qkvwb   = (__hip_bfloat16*)alloc(12L*1152*384/2);
    __hip_bfloat16* projwb  = (__hip_bfloat16*)alloc(12L*384*384/2);
    __hip_bfloat16* fc1wb   = (__hip_bfloat16*)alloc(12L*1536*384/2);
    __hip_bfloat16* fc2wb   = (__hip_bfloat16*)alloc(12L*384*1536/2);
    __hip_bfloat16* apoutwb = (__hip_bfloat16*)alloc(384L*384/2);

    // ---- setup: grid-stride conversion + W2/b2 prep + x cls rows ----
    cvt_all_k<<<CVTB + 5, 256, 0, stream>>>(
        qkv_w, proj_w, fc1_w, fc2_w, ap_out_w,
        qkvwb, projwb, fc1wb, fc2wb, apoutwb, vT,
        ap_in_w, ap_in_b, fp_w, fp_b, cls_tok, pos_emb, W2, b2, x);

    // ---- tokenizer ----
    prep_head_k<<<4, 64, 0, stream>>>(W2, b2, hGm);
    tok_attn_k<<<dim3(196,4,2), 1024, 0, stream>>>(img, hGm, W2, b2, pooledb);
    outproj_x_k<<<dim3(25,6), 64, 0, stream>>>(pooledb, apoutwb, ap_out_b, pos_emb, x);

    // ---- ViT trunk (5 dispatches per layer, column-parallel; R8) ----
    for (int i = 0; i < 12; ++i) {
        ln_gemm_k<1><<<dim3(25,18), 64, 0, stream>>>(
            x, ln1_g + i*384, ln1_b + i*384, qkvwb + (long)i*1152*384,
            qkv_b + i*1152, qb, kb, vT, 394, 1152);
        attn_flash_k<<<dim3(13,12), 64, 0, stream>>>(qb, kb, vT, attnb);
        gemm_mfma_k<false,true,false><<<dim3(25,6,1), 64, 0, stream>>>(
            attnb, projwb + (long)i*384*384, proj_b + i*384, x, x,
            394, 384, 384, 384, 384, 384, 384, 0);
        ln_gemm_k<2><<<dim3(25,24), 64, 0, stream>>>(
            x, ln2_g + i*384, ln2_b + i*384, fc1wb + (long)i*1536*384,
            fc1_b + i*1536, hbufb, nullptr, nullptr, 394, 1536);
        fc2_2w_k<<<dim3(25,6), 128, 0, stream>>>(
            hbufb, fc2wb + (long)i*384*1536, fc2_b + i*384, x);
    }

    // ---- head ----
    head_k<<<10, 256, 0, stream>>>(x, norm_g, norm_b, head_w, head_b, out);
}